// Round 5
// baseline (22.368 us; speedup 1.0000x reference)
//
#include <hip/hip_runtime.h>

// out[b] = (x[b] @ Wv + bv) @ Wo + bo   (reference collapses: x broadcast over
// seq makes q/k/v seq-constant -> softmax exactly uniform -> attn@v == v ->
// row 0 of o-proj = v@Wo+bo). Wq/bq/Wk/bk mathematically unused.
//
// Single fused kernel (plus a 4-byte memset for the barrier counter).
// 64 blocks x 1024 threads. Block = (strip: 32 output cols, kc: 512 K-rows).
// Per-wave W reads: 8 rows x 128 B = full cache lines, perfectly coalesced.
// Leg1 -> partials P1[kc][b][c] (32 KB ws) -> lean grid barrier ->
// each block rebuilds its t-slice in LDS -> leg2 -> 2-way atomicAdd into out
// (out pre-initialized to bo by kc==0 blocks BEFORE the barrier, published by
// the barrier's release fence).
//
// Barrier: one arrive + one RELAXED poller per block (no acquire-invalidate
// storm -- that was round 4's ~8 us mistake), single release fence before
// arrive, single acquire fence after.

namespace {

constexpr int CD     = 1024;  // C
constexpr int BN     = 4;     // B
constexpr int NBLK   = 64;    // grid
constexpr int NSTRIP = 32;    // col strips
constexpr int SW     = 32;    // strip width (cols)  -> 128 B rows
constexpr int KROWS  = 512;   // rows per k-chunk (2 chunks)
constexpr int NT     = 1024;  // threads per block

__global__ __launch_bounds__(NT, 1)
void fused_attn(const float* __restrict__ x,
                const float* __restrict__ Wv, const float* __restrict__ bv,
                const float* __restrict__ Wo, const float* __restrict__ bo,
                float* __restrict__ out,
                int* __restrict__ cnt, float* __restrict__ P1)
{
    __shared__ float red[16 * 128];   // [wave][cg*16 + j*4 + b]   8 KB
    __shared__ float ts[BN * KROWS];  // t slice for this kc        8 KB

    const int tid   = threadIdx.x;
    const int strip = blockIdx.x & (NSTRIP - 1);
    const int kc    = blockIdx.x >> 5;          // 0..1
    const int cg    = tid & 7;                  // float4 col group (8 -> 32 cols)
    const int ks    = tid >> 3;                 // k-slice 0..127
    const int lane  = tid & 63;
    const int wv    = tid >> 6;                 // wave 0..15
    const int i0    = strip * SW + cg * 4;

    // ================= leg 1: P1[kc][b][i] = sum_{r in kc} x[b][r]*Wv[r][i]
    float a[4][4];
#pragma unroll
    for (int j = 0; j < 4; ++j)
#pragma unroll
        for (int b = 0; b < BN; ++b) a[j][b] = 0.f;

#pragma unroll
    for (int rr = 0; rr < 4; ++rr) {
        const int r = kc * KROWS + rr * 128 + ks;
        const float4 w4 = *(const float4*)(Wv + (size_t)r * CD + i0);
        float xb[BN];
#pragma unroll
        for (int b = 0; b < BN; ++b) xb[b] = x[b * CD + r];
#pragma unroll
        for (int b = 0; b < BN; ++b) {
            a[0][b] = fmaf(xb[b], w4.x, a[0][b]);
            a[1][b] = fmaf(xb[b], w4.y, a[1][b]);
            a[2][b] = fmaf(xb[b], w4.z, a[2][b]);
            a[3][b] = fmaf(xb[b], w4.w, a[3][b]);
        }
    }

    // reduce over ks within wave (lane bits 3..5); every lane keeps its cg-sum
#pragma unroll
    for (int s = 8; s < 64; s <<= 1)
#pragma unroll
        for (int j = 0; j < 4; ++j)
#pragma unroll
            for (int b = 0; b < BN; ++b)
                a[j][b] += __shfl_xor(a[j][b], s, 64);

    if (lane < 8) {                    // lane == cg for lanes 0..7
#pragma unroll
        for (int j = 0; j < 4; ++j)
#pragma unroll
            for (int b = 0; b < BN; ++b)
                red[wv * 128 + lane * 16 + j * 4 + b] = a[j][b];
    }
    __syncthreads();

    if (tid < 128) {
        const int col = tid >> 2, b = tid & 3;
        const int idx = (col >> 2) * 16 + (col & 3) * 4 + b;
        float s = 0.f;
#pragma unroll
        for (int w = 0; w < 16; ++w) s += red[w * 128 + idx];
        P1[kc * (BN * CD) + b * CD + strip * SW + col] = s;
        // pre-barrier: kc==0 blocks seed out with the bias (published by the
        // release fence below; leg-2 atomics then accumulate on top)
        if (kc == 0) out[b * CD + strip * SW + col] = bo[strip * SW + col];
    }

    // ================= grid barrier (lean: 1 arriver + 1 relaxed poller/block)
    __syncthreads();   // all P1/out stores drained (vmcnt(0) at barrier)
    if (tid == 0) {
        __threadfence();                                   // release: publish P1 + out-init
        __hip_atomic_fetch_add(cnt, 1, __ATOMIC_RELAXED, __HIP_MEMORY_SCOPE_AGENT);
        while (__hip_atomic_load(cnt, __ATOMIC_RELAXED, __HIP_MEMORY_SCOPE_AGENT) != NBLK)
            __builtin_amdgcn_s_sleep(1);
        __threadfence();                                   // acquire: see remote P1
    }
    __syncthreads();

    // ================= rebuild t slice for this kc: t[b][c] = bv[c] + P1[0]+P1[1]
#pragma unroll
    for (int l = tid; l < BN * KROWS; l += NT) {
        const int b  = l >> 9;
        const int rl = l & (KROWS - 1);
        const int c  = kc * KROWS + rl;
        ts[l] = bv[c] + P1[0 * (BN * CD) + b * CD + c]
                      + P1[1 * (BN * CD) + b * CD + c];
    }
    __syncthreads();

    // ================= leg 2: out[b][i] += sum_{c in kc} t[b][c]*Wo[c][i]
#pragma unroll
    for (int j = 0; j < 4; ++j)
#pragma unroll
        for (int b = 0; b < BN; ++b) a[j][b] = 0.f;

#pragma unroll
    for (int rr = 0; rr < 4; ++rr) {
        const int rl = rr * 128 + ks;
        const int c  = kc * KROWS + rl;
        const float4 w4 = *(const float4*)(Wo + (size_t)c * CD + i0);
        float xb[BN];
#pragma unroll
        for (int b = 0; b < BN; ++b) xb[b] = ts[b * KROWS + rl];
#pragma unroll
        for (int b = 0; b < BN; ++b) {
            a[0][b] = fmaf(xb[b], w4.x, a[0][b]);
            a[1][b] = fmaf(xb[b], w4.y, a[1][b]);
            a[2][b] = fmaf(xb[b], w4.z, a[2][b]);
            a[3][b] = fmaf(xb[b], w4.w, a[3][b]);
        }
    }

#pragma unroll
    for (int s = 8; s < 64; s <<= 1)
#pragma unroll
        for (int j = 0; j < 4; ++j)
#pragma unroll
            for (int b = 0; b < BN; ++b)
                a[j][b] += __shfl_xor(a[j][b], s, 64);

    if (lane < 8) {
#pragma unroll
        for (int j = 0; j < 4; ++j)
#pragma unroll
            for (int b = 0; b < BN; ++b)
                red[wv * 128 + lane * 16 + j * 4 + b] = a[j][b];
    }
    __syncthreads();

    if (tid < 128) {
        const int col = tid >> 2, b = tid & 3;
        const int idx = (col >> 2) * 16 + (col & 3) * 4 + b;
        float s = 0.f;
#pragma unroll
        for (int w = 0; w < 16; ++w) s += red[w * 128 + idx];
        atomicAdd(&out[b * CD + strip * SW + col], s);  // 2-way contention only
    }
}

} // namespace

extern "C" void kernel_launch(void* const* d_in, const int* in_sizes, int n_in,
                              void* d_out, int out_size, void* d_ws, size_t ws_size,
                              hipStream_t stream)
{
    // setup_inputs() order: x, Wq, bq, Wk, bk, Wv, bv, Wo, bo  (all fp32)
    const float* x  = (const float*)d_in[0];
    const float* Wv = (const float*)d_in[5];
    const float* bv = (const float*)d_in[6];
    const float* Wo = (const float*)d_in[7];
    const float* bo = (const float*)d_in[8];
    float* out = (float*)d_out;

    int*   cnt = (int*)d_ws;                 // 1 int, zeroed every call
    float* P1  = (float*)d_ws + 16;          // [2][4][1024] partials (32 KB)

    hipMemsetAsync(d_ws, 0, sizeof(int), stream);
    fused_attn<<<NBLK, NT, 0, stream>>>(x, Wv, bv, Wo, bo, out, cnt, P1);
}